// Round 13
// baseline (92.460 us; speedup 1.0000x reference)
//
#include <hip/hip_runtime.h>
#include <hip/hip_bf16.h>
#include <math.h>

using short8 = __attribute__((ext_vector_type(8))) short;
using f32x4  = __attribute__((ext_vector_type(4))) float;
using fv4    = __attribute__((ext_vector_type(4))) float;

#define EMB 768
#define CD  64
#define NSCEN 19
#define KSTEPS 24            // 768 / 32
#define NCHUNKS (25 * 4)     // (24 emb + 1 bag) k-steps x 4 col-tiles, 512 bf16 each
#define QB 12288             // ushorts per LDS B quarter-buffer (24 KB = 6 k-steps)
#define BM 128               // rows per block

__device__ __forceinline__ ushort f2bf(float x) {
    unsigned u = __float_as_uint(x);
    u += 0x7FFFu + ((u >> 16) & 1u);   // RNE
    return (ushort)(u >> 16);
}

// packed f32x2 -> bf16x2 (v_cvt_pk_bf16_f32)
__device__ __forceinline__ uint cvt2(float x, float y) {
    __hip_bfloat162 h = __float22bfloat162_rn(make_float2(x, y));
    union { __hip_bfloat162 h; uint u; } c;
    c.h = h;
    return c.u;
}

// async global->LDS, 16 B per lane; LDS dest = wave-uniform base + lane*16
#define GLD(gp, lp)                                                          \
    __builtin_amdgcn_global_load_lds(                                        \
        (const __attribute__((address_space(1))) unsigned int*)(gp),         \
        (__attribute__((address_space(3))) unsigned int*)(lp), 16, 0, 0)

// Pre-fragment B = [W1(768x64) ; P(32x64)] into bf16 wave-chunks of 512 elems:
// chunk c = ks*4+ct; element r = lane*8+j  <->  B[k = ks*32+(lane>>4)*8+j][col = ct*16+(lane&15)]
__global__ void prep_W1T(const float* __restrict__ table,
                         const float* __restrict__ W1,
                         ushort* __restrict__ W1T) {
    int e = blockIdx.x * 256 + threadIdx.x;      // 0 .. 51200
    if (e >= NCHUNKS * 512) return;
    int chunk = e >> 9, r = e & 511;
    int lane = r >> 3, j = r & 7;
    int ks = chunk >> 2, ct = chunk & 3;
    int col = ct * 16 + (lane & 15);
    int k = ks * 32 + ((lane >> 4) << 3) + j;
    float v = 0.f;
    if (k < EMB) {
        v = W1[(size_t)k * CD + col];
    } else {
        int s = k - EMB;
        if (s < NSCEN) {
            for (int d = 0; d < 16; ++d)
                v += table[s * 16 + d] * W1[(size_t)(EMB + s * 16 + d) * CD + col];
        }
    }
    W1T[e] = f2bf(v);
}

__global__ __launch_bounds__(512, 4)
void scorer_mfma(const float* __restrict__ emb,
                 const int* __restrict__ ids,
                 const float* __restrict__ mask,
                 const ushort* __restrict__ W1T,
                 const float* __restrict__ b1,
                 const float* __restrict__ W2,
                 const float* __restrict__ b2,
                 float* __restrict__ out) {
    __shared__ __align__(16) ushort Bq[2][QB];       // 2 x 24 KB B quarter-buffers
    __shared__ __align__(16) ushort Pb[2048];        // bag B chunk (4 KB), loaded once
    __shared__ __align__(16) ushort bagb[8][16][32]; // per-wave bag rows (wave-local)

    const int t    = threadIdx.x;
    const int w    = t >> 6;       // wave 0..7, owns rows w*16..w*16+15
    const int lane = t & 63;
    const int lr   = lane & 15;
    const int lg   = lane >> 4;
    const int row0 = blockIdx.x * BM;

    // quarter fill: 24 KB direct-to-LDS (3 x 16 B per thread), issued async
#define FILLQ(bufi, q) do {                                                   \
    const char* _gb = (const char*)W1T + (size_t)(q) * 24576 + w * 1024 + lane * 16; \
    char*       _lb = (char*)&Bq[bufi][0] + w * 1024;                         \
    GLD(_gb,         _lb);                                                    \
    GLD(_gb + 8192,  _lb + 8192);                                             \
    GLD(_gb + 16384, _lb + 16384);                                            \
} while (0)

    // ================== startup: issue ALL startup vmem, then VALU histogram =====
    const int hrow = row0 + w * 16 + lr;
    const int*   idrow = ids  + (size_t)hrow * 32 + lg * 8;
    const float* mrow  = mask + (size_t)hrow * 32 + lg * 8;
    int4   iv0 = ((const int4*)idrow)[0],  iv1 = ((const int4*)idrow)[1];
    float4 mv0 = ((const float4*)mrow)[0], mv1 = ((const float4*)mrow)[1];

    const float* ap = emb + (size_t)(row0 + w * 16 + lr) * EMB + (lg << 3);
    fv4 aA[2], aB[2];
#define LOADA(dst, kks) do {                                   \
    const float* _p = ap + (kks) * 32;                         \
    dst[0] = *(const fv4*)(_p);                                \
    dst[1] = *(const fv4*)(_p + 4);                            \
} while (0)
    LOADA(aA, 0);

    FILLQ(0, 0);                       // quarter 0 -> Bq0
    FILLQ(1, 1);                       // quarter 1 -> Bq1
    if (w < 4)                         // bag P chunk (W1T bytes [98304, +4096)) -> Pb
        GLD((const char*)W1T + 98304 + w * 1024 + lane * 16, (char*)Pb + w * 1024);

    // ================== histogram: pure VALU, in-register, no atomics ============
    float bin[NSCEN];
#pragma unroll
    for (int s = 0; s < NSCEN; ++s) bin[s] = 0.f;
    float cnt = 0.f;
#define HSLOT(idv, mvv) do {                                   \
    cnt += mvv;                                                \
    _Pragma("unroll")                                          \
    for (int s = 0; s < NSCEN; ++s)                            \
        bin[s] += (idv == s) ? mvv : 0.f;                      \
} while (0)
    HSLOT(iv0.x, mv0.x); HSLOT(iv0.y, mv0.y); HSLOT(iv0.z, mv0.z); HSLOT(iv0.w, mv0.w);
    HSLOT(iv1.x, mv1.x); HSLOT(iv1.y, mv1.y); HSLOT(iv1.z, mv1.z); HSLOT(iv1.w, mv1.w);
#undef HSLOT
    cnt += __shfl_xor(cnt, 16);
    cnt += __shfl_xor(cnt, 32);
#pragma unroll
    for (int s = 0; s < NSCEN; ++s) {
        bin[s] += __shfl_xor(bin[s], 16);
        bin[s] += __shfl_xor(bin[s], 32);
    }
    {
        float rc = 1.0f / fmaxf(cnt, 1.0f);
        if (lane < 16) {   // lane l writes row w*16+l (wave-local)
            uint u[16];
#pragma unroll
            for (int p = 0; p < 9; ++p) u[p] = cvt2(bin[2 * p] * rc, bin[2 * p + 1] * rc);
            u[9] = cvt2(bin[18] * rc, 0.f);
#pragma unroll
            for (int p = 10; p < 16; ++p) u[p] = 0u;
            ushort* bp = &bagb[w][lane][0];
#pragma unroll
            for (int q = 0; q < 4; ++q)
                *(uint4*)(bp + q * 8) = make_uint4(u[4 * q], u[4 * q + 1], u[4 * q + 2], u[4 * q + 3]);
        }
    }
    __syncthreads();   // Bq0, Bq1, Pb all resident (drain hidden under histogram)

    // ================== MFMA stream =============================================
    f32x4 acc[4];
#pragma unroll
    for (int j = 0; j < 4; ++j) acc[j] = (f32x4)0.f;

    short8 bqr[4];
#define LDSB(bufi, ksl) do {                                   \
    const ushort* _l = &Bq[bufi][(ksl) * 2048 + lane * 8];     \
    bqr[0] = *(const short8*)(_l);                             \
    bqr[1] = *(const short8*)(_l + 512);                       \
    bqr[2] = *(const short8*)(_l + 1024);                      \
    bqr[3] = *(const short8*)(_l + 1536);                      \
} while (0)

#define STEP(areg) do {                                                     \
    union { uint u[4]; short8 s; } _c;                                      \
    _c.u[0] = cvt2(areg[0][0], areg[0][1]);                                 \
    _c.u[1] = cvt2(areg[0][2], areg[0][3]);                                 \
    _c.u[2] = cvt2(areg[1][0], areg[1][1]);                                 \
    _c.u[3] = cvt2(areg[1][2], areg[1][3]);                                 \
    acc[0] = __builtin_amdgcn_mfma_f32_16x16x32_bf16(_c.s, bqr[0], acc[0], 0, 0, 0); \
    acc[1] = __builtin_amdgcn_mfma_f32_16x16x32_bf16(_c.s, bqr[1], acc[1], 0, 0, 0); \
    acc[2] = __builtin_amdgcn_mfma_f32_16x16x32_bf16(_c.s, bqr[2], acc[2], 0, 0, 0); \
    acc[3] = __builtin_amdgcn_mfma_f32_16x16x32_bf16(_c.s, bqr[3], acc[3], 0, 0, 0); \
} while (0)

#define QUARTER(bufi, qs) do {                                              \
    _Pragma("unroll")                                                       \
    for (int _ksl = 0; _ksl < 6; ++_ksl) {                                  \
        const int _ks = (qs) + _ksl;                                        \
        LDSB(bufi, _ksl);                                                   \
        if ((_ks & 1) == 0) {                                               \
            if (_ks + 1 <= 23) LOADA(aB, _ks + 1);                          \
            STEP(aA);                                                       \
        } else {                                                            \
            if (_ks + 1 <= 23) LOADA(aA, _ks + 1);                          \
            STEP(aB);                                                       \
        }                                                                   \
    }                                                                       \
} while (0)

    QUARTER(0, 0);
    __syncthreads();   // all waves done with Bq0

    FILLQ(0, 2);       // async q2 -> Bq0, lands during next quarter's compute
    QUARTER(1, 6);
    __syncthreads();   // q2 resident (drain hidden under QUARTER)

    FILLQ(1, 3);       // async q3 -> Bq1
    QUARTER(0, 12);
    __syncthreads();   // q3 resident

    QUARTER(1, 18);
    {   // bag k-step: A from bagb (wave-local), B = Pb
        short8 ab = *(const short8*)&bagb[w][lr][lg << 3];
        const ushort* _l = &Pb[lane * 8];
        short8 p0 = *(const short8*)(_l);
        short8 p1 = *(const short8*)(_l + 512);
        short8 p2 = *(const short8*)(_l + 1024);
        short8 p3 = *(const short8*)(_l + 1536);
        acc[0] = __builtin_amdgcn_mfma_f32_16x16x32_bf16(ab, p0, acc[0], 0, 0, 0);
        acc[1] = __builtin_amdgcn_mfma_f32_16x16x32_bf16(ab, p1, acc[1], 0, 0, 0);
        acc[2] = __builtin_amdgcn_mfma_f32_16x16x32_bf16(ab, p2, acc[2], 0, 0, 0);
        acc[3] = __builtin_amdgcn_mfma_f32_16x16x32_bf16(ab, p3, acc[3], 0, 0, 0);
    }

    // ================== epilogue: bias + relu + dot(W2) + tanh ===================
    float b1v[4], w2v[4];
#pragma unroll
    for (int ct = 0; ct < 4; ++ct) {
        int c = ct * 16 + lr;
        b1v[ct] = b1[c];
        w2v[ct] = W2[c];
    }
    const float b2v = b2[0];
#pragma unroll
    for (int r = 0; r < 4; ++r) {
        float p = 0.f;
#pragma unroll
        for (int ct = 0; ct < 4; ++ct) {
            float h = acc[ct][r] + b1v[ct];
            p += fmaxf(h, 0.f) * w2v[ct];
        }
        p += __shfl_xor(p, 1);
        p += __shfl_xor(p, 2);
        p += __shfl_xor(p, 4);
        p += __shfl_xor(p, 8);
        if (lr == 0)
            out[row0 + w * 16 + (lg << 2) + r] = tanhf(p + b2v);
    }
#undef FILLQ
#undef LOADA
#undef LDSB
#undef STEP
#undef QUARTER
}

extern "C" void kernel_launch(void* const* d_in, const int* in_sizes, int n_in,
                              void* d_out, int out_size, void* d_ws, size_t ws_size,
                              hipStream_t stream) {
    const float* emb   = (const float*)d_in[0];
    const int*   ids   = (const int*)d_in[1];
    const float* mask  = (const float*)d_in[2];
    const float* table = (const float*)d_in[3];
    const float* W1    = (const float*)d_in[4];
    const float* b1    = (const float*)d_in[5];
    const float* W2    = (const float*)d_in[6];
    const float* b2    = (const float*)d_in[7];
    float* out  = (float*)d_out;
    ushort* W1T = (ushort*)d_ws;   // 51200 bf16 = 100 KB

    prep_W1T<<<200, 256, 0, stream>>>(table, W1, W1T);
    const int nblocks = out_size / BM;   // 1024
    scorer_mfma<<<nblocks, 512, 0, stream>>>(emb, ids, mask, W1T, b1, W2, b2, out);
}

// Round 14
// 91.629 us; speedup vs baseline: 1.0091x; 1.0091x over previous
//
#include <hip/hip_runtime.h>
#include <hip/hip_bf16.h>
#include <math.h>

using short8 = __attribute__((ext_vector_type(8))) short;
using f32x4  = __attribute__((ext_vector_type(4))) float;
using fv4    = __attribute__((ext_vector_type(4))) float;

#define EMB 768
#define CD  64
#define NSCEN 19
#define KSTEPS 24            // 768 / 32
#define NCHUNKS (25 * 4)     // (24 emb + 1 bag) k-steps x 4 col-tiles, 512 bf16 each
#define QB 14336             // ushorts per LDS B quarter-buffer (28 KB)
#define BM 128               // rows per block

__device__ __forceinline__ ushort f2bf(float x) {
    unsigned u = __float_as_uint(x);
    u += 0x7FFFu + ((u >> 16) & 1u);   // RNE
    return (ushort)(u >> 16);
}

// packed f32x2 -> bf16x2 (v_cvt_pk_bf16_f32)
__device__ __forceinline__ uint cvt2(float x, float y) {
    __hip_bfloat162 h = __float22bfloat162_rn(make_float2(x, y));
    union { __hip_bfloat162 h; uint u; } c;
    c.h = h;
    return c.u;
}

// Pre-fragment B = [W1(768x64) ; P(32x64)] into bf16 wave-chunks of 512 elems:
// chunk c = ks*4+ct; element r = lane*8+j  <->  B[k = ks*32+(lane>>4)*8+j][col = ct*16+(lane&15)]
__global__ void prep_W1T(const float* __restrict__ table,
                         const float* __restrict__ W1,
                         ushort* __restrict__ W1T) {
    int e = blockIdx.x * 256 + threadIdx.x;      // 0 .. 51200
    if (e >= NCHUNKS * 512) return;
    int chunk = e >> 9, r = e & 511;
    int lane = r >> 3, j = r & 7;
    int ks = chunk >> 2, ct = chunk & 3;
    int col = ct * 16 + (lane & 15);
    int k = ks * 32 + ((lane >> 4) << 3) + j;
    float v = 0.f;
    if (k < EMB) {
        v = W1[(size_t)k * CD + col];
    } else {
        int s = k - EMB;
        if (s < NSCEN) {
            for (int d = 0; d < 16; ++d)
                v += table[s * 16 + d] * W1[(size_t)(EMB + s * 16 + d) * CD + col];
        }
    }
    W1T[e] = f2bf(v);
}

__global__ __launch_bounds__(512, 4)
void scorer_mfma(const float* __restrict__ emb,
                 const int* __restrict__ ids,
                 const float* __restrict__ mask,
                 const ushort* __restrict__ W1T,
                 const float* __restrict__ b1,
                 const float* __restrict__ W2,
                 const float* __restrict__ b2,
                 float* __restrict__ out) {
    __shared__ __align__(16) ushort Bq[2][QB];       // 2 x 28 KB B quarter-buffers
    __shared__ __align__(16) ushort bagb[8][16][32]; // per-wave bag rows (wave-local)

    const int t    = threadIdx.x;
    const int w    = t >> 6;       // wave 0..7, owns rows w*16..w*16+15
    const int lane = t & 63;
    const int lr   = lane & 15;
    const int lg   = lane >> 4;
    const int row0 = blockIdx.x * BM;

    // ================== startup vmem burst (before any VALU phase) ===============
    // bag inputs: 4 lanes per row; lane l -> row w*16+(l&15), slot-quarter q=(l>>4)
    const int hrow = row0 + w * 16 + lr;
    const int*   idrow = ids  + (size_t)hrow * 32 + lg * 8;
    const float* mrow  = mask + (size_t)hrow * 32 + lg * 8;
    int4   iv0 = ((const int4*)idrow)[0],  iv1 = ((const int4*)idrow)[1];
    float4 mv0 = ((const float4*)mrow)[0], mv1 = ((const float4*)mrow)[1];

    const float* ap = emb + (size_t)(row0 + w * 16 + lr) * EMB + (lg << 3);
    fv4 aR[3][2];   // A-stream ring, prefetch depth 2
#define LOADA(dst, kks) do {                                   \
    const float* _p = ap + (kks) * 32;                         \
    dst[0] = *(const fv4*)(_p);                                \
    dst[1] = *(const fv4*)(_p + 4);                            \
} while (0)
    LOADA(aR[0], 0);   // k-steps 0,1 in flight during histogram
    LOADA(aR[1], 1);

    uint4 f0, f1, f2, f3;
#define ISSUE_FILL(qs) do {                                                  \
    const uint* _g = (const uint*)((const char*)W1T + (size_t)(qs) * 4096);  \
    f0 = *(const uint4*)(_g + (t)        * 4);                               \
    f1 = *(const uint4*)(_g + (t + 512)  * 4);                               \
    f2 = *(const uint4*)(_g + (t + 1024) * 4);                               \
    if (t < 256) f3 = *(const uint4*)(_g + (t + 1536) * 4);                  \
} while (0)
#define WRITE_FILL(bufi) do {                                                \
    uint* _l = (uint*)&Bq[bufi][0];                                          \
    *(uint4*)(_l + (t)        * 4) = f0;                                     \
    *(uint4*)(_l + (t + 512)  * 4) = f1;                                     \
    *(uint4*)(_l + (t + 1024) * 4) = f2;                                     \
    if (t < 256) *(uint4*)(_l + (t + 1536) * 4) = f3;                        \
} while (0)
    ISSUE_FILL(0);   // quarter 0 in flight during histogram

    // ================== histogram: pure VALU, in-register, no atomics ============
    float bin[NSCEN];
#pragma unroll
    for (int s = 0; s < NSCEN; ++s) bin[s] = 0.f;
    float cnt = 0.f;
#define HSLOT(idv, mvv) do {                                   \
    cnt += mvv;                                                \
    _Pragma("unroll")                                          \
    for (int s = 0; s < NSCEN; ++s)                            \
        bin[s] += (idv == s) ? mvv : 0.f;                      \
} while (0)
    HSLOT(iv0.x, mv0.x); HSLOT(iv0.y, mv0.y); HSLOT(iv0.z, mv0.z); HSLOT(iv0.w, mv0.w);
    HSLOT(iv1.x, mv1.x); HSLOT(iv1.y, mv1.y); HSLOT(iv1.z, mv1.z); HSLOT(iv1.w, mv1.w);
#undef HSLOT
    // merge the four slot-quarter lanes (l ^16, ^32)
    cnt += __shfl_xor(cnt, 16);
    cnt += __shfl_xor(cnt, 32);
#pragma unroll
    for (int s = 0; s < NSCEN; ++s) {
        bin[s] += __shfl_xor(bin[s], 16);
        bin[s] += __shfl_xor(bin[s], 32);
    }
    {
        float rc = 1.0f / fmaxf(cnt, 1.0f);
        if (lane < 16) {   // lane l writes row w*16+l (wave-local: no barrier needed)
            uint u[16];
#pragma unroll
            for (int p = 0; p < 9; ++p) u[p] = cvt2(bin[2 * p] * rc, bin[2 * p + 1] * rc);
            u[9] = cvt2(bin[18] * rc, 0.f);
#pragma unroll
            for (int p = 10; p < 16; ++p) u[p] = 0u;
            ushort* bp = &bagb[w][lane][0];
#pragma unroll
            for (int q = 0; q < 4; ++q)
                *(uint4*)(bp + q * 8) = make_uint4(u[4 * q], u[4 * q + 1], u[4 * q + 2], u[4 * q + 3]);
        }
    }

    WRITE_FILL(0);     // Bq0 <- quarter 0
    ISSUE_FILL(6);     // quarter 1
    __syncthreads();   // Bq0 ready

    // ================== MFMA stream: A = only steady-state vmem traffic ==========
    f32x4 acc[4];
#pragma unroll
    for (int j = 0; j < 4; ++j) acc[j] = (f32x4)0.f;

    short8 bqr[4];
#define LDSB(bufi, ksl) do {                                   \
    const ushort* _l = &Bq[bufi][(ksl) * 2048 + lane * 8];     \
    bqr[0] = *(const short8*)(_l);                             \
    bqr[1] = *(const short8*)(_l + 512);                       \
    bqr[2] = *(const short8*)(_l + 1024);                      \
    bqr[3] = *(const short8*)(_l + 1536);                      \
} while (0)

#define STEP(areg) do {                                                     \
    union { uint u[4]; short8 s; } _c;                                      \
    _c.u[0] = cvt2(areg[0][0], areg[0][1]);                                 \
    _c.u[1] = cvt2(areg[0][2], areg[0][3]);                                 \
    _c.u[2] = cvt2(areg[1][0], areg[1][1]);                                 \
    _c.u[3] = cvt2(areg[1][2], areg[1][3]);                                 \
    acc[0] = __builtin_amdgcn_mfma_f32_16x16x32_bf16(_c.s, bqr[0], acc[0], 0, 0, 0); \
    acc[1] = __builtin_amdgcn_mfma_f32_16x16x32_bf16(_c.s, bqr[1], acc[1], 0, 0, 0); \
    acc[2] = __builtin_amdgcn_mfma_f32_16x16x32_bf16(_c.s, bqr[2], acc[2], 0, 0, 0); \
    acc[3] = __builtin_amdgcn_mfma_f32_16x16x32_bf16(_c.s, bqr[3], acc[3], 0, 0, 0); \
} while (0)

// depth-2 A prefetch: at step ks consume aR[ks%3], issue load for ks+2
#define QUARTER(bufi, qs) do {                                              \
    _Pragma("unroll")                                                       \
    for (int _ksl = 0; _ksl < 6; ++_ksl) {                                  \
        const int _ks = (qs) + _ksl;                                        \
        LDSB(bufi, _ksl);                                                   \
        if (_ks + 2 <= 23) LOADA(aR[(_ks + 2) % 3], _ks + 2);               \
        STEP(aR[_ks % 3]);                                                  \
    }                                                                       \
} while (0)

    // Q0: compute from Bq0; fill Bq1 (q1 regs in flight), issue q2
    WRITE_FILL(1);
    ISSUE_FILL(12);
    QUARTER(0, 0);
    __syncthreads();   // Bq1 ready; Bq0 free

    // Q1: compute from Bq1; fill Bq0 with q2, issue q3
    WRITE_FILL(0);
    ISSUE_FILL(18);
    QUARTER(1, 6);
    __syncthreads();   // Bq0 ready; Bq1 free

    // Q2: compute from Bq0; fill Bq1 with q3 (k-steps 18-24 incl. bag chunk)
    WRITE_FILL(1);
    QUARTER(0, 12);
    __syncthreads();   // Bq1 ready

    // Q3: compute from Bq1 (6 emb steps + bag step at local chunk 6)
    QUARTER(1, 18);
    {
        short8 ab = *(const short8*)&bagb[w][lr][lg << 3];
        LDSB(1, 6);
        acc[0] = __builtin_amdgcn_mfma_f32_16x16x32_bf16(ab, bqr[0], acc[0], 0, 0, 0);
        acc[1] = __builtin_amdgcn_mfma_f32_16x16x32_bf16(ab, bqr[1], acc[1], 0, 0, 0);
        acc[2] = __builtin_amdgcn_mfma_f32_16x16x32_bf16(ab, bqr[2], acc[2], 0, 0, 0);
        acc[3] = __builtin_amdgcn_mfma_f32_16x16x32_bf16(ab, bqr[3], acc[3], 0, 0, 0);
    }

    // ================== epilogue: bias + relu + dot(W2) + tanh ===================
    float b1v[4], w2v[4];
#pragma unroll
    for (int ct = 0; ct < 4; ++ct) {
        int c = ct * 16 + lr;
        b1v[ct] = b1[c];
        w2v[ct] = W2[c];
    }
    const float b2v = b2[0];
#pragma unroll
    for (int r = 0; r < 4; ++r) {
        float p = 0.f;
#pragma unroll
        for (int ct = 0; ct < 4; ++ct) {
            float h = acc[ct][r] + b1v[ct];
            p += fmaxf(h, 0.f) * w2v[ct];
        }
        p += __shfl_xor(p, 1);
        p += __shfl_xor(p, 2);
        p += __shfl_xor(p, 4);
        p += __shfl_xor(p, 8);
        if (lr == 0)
            out[row0 + w * 16 + (lg << 2) + r] = tanhf(p + b2v);
    }
#undef ISSUE_FILL
#undef WRITE_FILL
#undef LOADA
#undef LDSB
#undef STEP
#undef QUARTER
}

extern "C" void kernel_launch(void* const* d_in, const int* in_sizes, int n_in,
                              void* d_out, int out_size, void* d_ws, size_t ws_size,
                              hipStream_t stream) {
    const float* emb   = (const float*)d_in[0];
    const int*   ids   = (const int*)d_in[1];
    const float* mask  = (const float*)d_in[2];
    const float* table = (const float*)d_in[3];
    const float* W1    = (const float*)d_in[4];
    const float* b1    = (const float*)d_in[5];
    const float* W2    = (const float*)d_in[6];
    const float* b2    = (const float*)d_in[7];
    float* out  = (float*)d_out;
    ushort* W1T = (ushort*)d_ws;   // 51200 bf16 = 100 KB

    prep_W1T<<<200, 256, 0, stream>>>(table, W1, W1T);
    const int nblocks = out_size / BM;   // 1024
    scorer_mfma<<<nblocks, 512, 0, stream>>>(emb, ids, mask, W1T, b1, W2, b2, out);
}

// Round 15
// 90.079 us; speedup vs baseline: 1.0264x; 1.0172x over previous
//
#include <hip/hip_runtime.h>
#include <hip/hip_bf16.h>
#include <math.h>

using short8 = __attribute__((ext_vector_type(8))) short;
using f32x4  = __attribute__((ext_vector_type(4))) float;
using fv4    = __attribute__((ext_vector_type(4))) float;

#define EMB 768
#define CD  64
#define NSCEN 19
#define KSTEPS 24            // 768 / 32
#define NCHUNKS (25 * 4)     // (24 emb + 1 bag) k-steps x 4 col-tiles, 512 bf16 each
#define QB 14336             // ushorts per LDS B quarter-buffer (28 KB)
#define BM 128               // rows per block

__device__ __forceinline__ ushort f2bf(float x) {
    unsigned u = __float_as_uint(x);
    u += 0x7FFFu + ((u >> 16) & 1u);   // RNE
    return (ushort)(u >> 16);
}

// packed f32x2 -> bf16x2 (v_cvt_pk_bf16_f32)
__device__ __forceinline__ uint cvt2(float x, float y) {
    __hip_bfloat162 h = __float22bfloat162_rn(make_float2(x, y));
    union { __hip_bfloat162 h; uint u; } c;
    c.h = h;
    return c.u;
}

// Pre-fragment B = [W1(768x64) ; P(32x64)] into bf16 wave-chunks of 512 elems:
// chunk c = ks*4+ct; element r = lane*8+j  <->  B[k = ks*32+(lane>>4)*8+j][col = ct*16+(lane&15)]
// v2: 4 elems/thread (same chunk/lane, j0 in {0,4}) -> one ushort4 store. Bit-identical output.
__global__ void prep_W1T(const float* __restrict__ table,
                         const float* __restrict__ W1,
                         ushort* __restrict__ W1T) {
    int e0 = (blockIdx.x * 256 + threadIdx.x) * 4;   // 0 .. 51196, grid 50x256
    if (e0 >= NCHUNKS * 512) return;
    int chunk = e0 >> 9, r = e0 & 511;
    int lane = r >> 3, j0 = r & 7;
    int ks = chunk >> 2, ct = chunk & 3;
    int col = ct * 16 + (lane & 15);
    int kbase = ks * 32 + ((lane >> 4) << 3) + j0;
    ushort res[4];
#pragma unroll
    for (int q = 0; q < 4; ++q) {
        int k = kbase + q;
        float v = 0.f;
        if (k < EMB) {
            v = W1[(size_t)k * CD + col];
        } else {
            int s = k - EMB;
            if (s < NSCEN) {
#pragma unroll
                for (int d = 0; d < 16; ++d)
                    v += table[s * 16 + d] * W1[(size_t)(EMB + s * 16 + d) * CD + col];
            }
        }
        res[q] = f2bf(v);
    }
    *(ushort4*)&W1T[e0] = make_ushort4(res[0], res[1], res[2], res[3]);
}

__global__ __launch_bounds__(512, 4)
void scorer_mfma(const float* __restrict__ emb,
                 const int* __restrict__ ids,
                 const float* __restrict__ mask,
                 const ushort* __restrict__ W1T,
                 const float* __restrict__ b1,
                 const float* __restrict__ W2,
                 const float* __restrict__ b2,
                 float* __restrict__ out) {
    __shared__ __align__(16) ushort Bq[2][QB];       // 2 x 28 KB B quarter-buffers
    __shared__ __align__(16) ushort bagb[8][16][32]; // per-wave bag rows (wave-local)

    const int t    = threadIdx.x;
    const int w    = t >> 6;       // wave 0..7, owns rows w*16..w*16+15
    const int lane = t & 63;
    const int lr   = lane & 15;
    const int lg   = lane >> 4;
    const int row0 = blockIdx.x * BM;

    // ================== startup vmem burst (before any VALU phase) ===============
    // bag inputs: 4 lanes per row; lane l -> row w*16+(l&15), slot-quarter q=(l>>4)
    const int hrow = row0 + w * 16 + lr;
    const int*   idrow = ids  + (size_t)hrow * 32 + lg * 8;
    const float* mrow  = mask + (size_t)hrow * 32 + lg * 8;
    int4   iv0 = ((const int4*)idrow)[0],  iv1 = ((const int4*)idrow)[1];
    float4 mv0 = ((const float4*)mrow)[0], mv1 = ((const float4*)mrow)[1];

    const float* ap = emb + (size_t)(row0 + w * 16 + lr) * EMB + (lg << 3);
    fv4 aA[2], aB[2];
#define LOADA(dst, kks) do {                                   \
    const float* _p = ap + (kks) * 32;                         \
    dst[0] = *(const fv4*)(_p);                                \
    dst[1] = *(const fv4*)(_p + 4);                            \
} while (0)
    LOADA(aA, 0);   // first A k-step in flight during histogram

    uint4 f0, f1, f2, f3;
#define ISSUE_FILL(qs) do {                                                  \
    const uint* _g = (const uint*)((const char*)W1T + (size_t)(qs) * 4096);  \
    f0 = *(const uint4*)(_g + (t)        * 4);                               \
    f1 = *(const uint4*)(_g + (t + 512)  * 4);                               \
    f2 = *(const uint4*)(_g + (t + 1024) * 4);                               \
    if (t < 256) f3 = *(const uint4*)(_g + (t + 1536) * 4);                  \
} while (0)
#define WRITE_FILL(bufi) do {                                                \
    uint* _l = (uint*)&Bq[bufi][0];                                          \
    *(uint4*)(_l + (t)        * 4) = f0;                                     \
    *(uint4*)(_l + (t + 512)  * 4) = f1;                                     \
    *(uint4*)(_l + (t + 1024) * 4) = f2;                                     \
    if (t < 256) *(uint4*)(_l + (t + 1536) * 4) = f3;                        \
} while (0)
    ISSUE_FILL(0);   // quarter 0 in flight during histogram

    // ================== histogram: pure VALU, in-register, no atomics ============
    float bin[NSCEN];
#pragma unroll
    for (int s = 0; s < NSCEN; ++s) bin[s] = 0.f;
    float cnt = 0.f;
#define HSLOT(idv, mvv) do {                                   \
    cnt += mvv;                                                \
    _Pragma("unroll")                                          \
    for (int s = 0; s < NSCEN; ++s)                            \
        bin[s] += (idv == s) ? mvv : 0.f;                      \
} while (0)
    HSLOT(iv0.x, mv0.x); HSLOT(iv0.y, mv0.y); HSLOT(iv0.z, mv0.z); HSLOT(iv0.w, mv0.w);
    HSLOT(iv1.x, mv1.x); HSLOT(iv1.y, mv1.y); HSLOT(iv1.z, mv1.z); HSLOT(iv1.w, mv1.w);
#undef HSLOT
    // merge the four slot-quarter lanes (l ^16, ^32)
    cnt += __shfl_xor(cnt, 16);
    cnt += __shfl_xor(cnt, 32);
#pragma unroll
    for (int s = 0; s < NSCEN; ++s) {
        bin[s] += __shfl_xor(bin[s], 16);
        bin[s] += __shfl_xor(bin[s], 32);
    }
    {
        float rc = 1.0f / fmaxf(cnt, 1.0f);
        if (lane < 16) {   // lane l writes row w*16+l (wave-local: no barrier needed)
            uint u[16];
#pragma unroll
            for (int p = 0; p < 9; ++p) u[p] = cvt2(bin[2 * p] * rc, bin[2 * p + 1] * rc);
            u[9] = cvt2(bin[18] * rc, 0.f);
#pragma unroll
            for (int p = 10; p < 16; ++p) u[p] = 0u;
            ushort* bp = &bagb[w][lane][0];
#pragma unroll
            for (int q = 0; q < 4; ++q)
                *(uint4*)(bp + q * 8) = make_uint4(u[4 * q], u[4 * q + 1], u[4 * q + 2], u[4 * q + 3]);
        }
    }

    WRITE_FILL(0);     // Bq0 <- quarter 0
    ISSUE_FILL(6);     // quarter 1
    __syncthreads();   // Bq0 ready

    // ================== MFMA stream: A = only steady-state vmem traffic ==========
    f32x4 acc[4];
#pragma unroll
    for (int j = 0; j < 4; ++j) acc[j] = (f32x4)0.f;

    short8 bqr[4];
#define LDSB(bufi, ksl) do {                                   \
    const ushort* _l = &Bq[bufi][(ksl) * 2048 + lane * 8];     \
    bqr[0] = *(const short8*)(_l);                             \
    bqr[1] = *(const short8*)(_l + 512);                       \
    bqr[2] = *(const short8*)(_l + 1024);                      \
    bqr[3] = *(const short8*)(_l + 1536);                      \
} while (0)

#define STEP(areg) do {                                                     \
    union { uint u[4]; short8 s; } _c;                                      \
    _c.u[0] = cvt2(areg[0][0], areg[0][1]);                                 \
    _c.u[1] = cvt2(areg[0][2], areg[0][3]);                                 \
    _c.u[2] = cvt2(areg[1][0], areg[1][1]);                                 \
    _c.u[3] = cvt2(areg[1][2], areg[1][3]);                                 \
    acc[0] = __builtin_amdgcn_mfma_f32_16x16x32_bf16(_c.s, bqr[0], acc[0], 0, 0, 0); \
    acc[1] = __builtin_amdgcn_mfma_f32_16x16x32_bf16(_c.s, bqr[1], acc[1], 0, 0, 0); \
    acc[2] = __builtin_amdgcn_mfma_f32_16x16x32_bf16(_c.s, bqr[2], acc[2], 0, 0, 0); \
    acc[3] = __builtin_amdgcn_mfma_f32_16x16x32_bf16(_c.s, bqr[3], acc[3], 0, 0, 0); \
} while (0)

#define QUARTER(bufi, qs) do {                                              \
    _Pragma("unroll")                                                       \
    for (int _ksl = 0; _ksl < 6; ++_ksl) {                                  \
        const int _ks = (qs) + _ksl;                                        \
        LDSB(bufi, _ksl);                                                   \
        if ((_ks & 1) == 0) {                                               \
            if (_ks + 1 <= 23) LOADA(aB, _ks + 1);                          \
            STEP(aA);                                                       \
        } else {                                                            \
            if (_ks + 1 <= 23) LOADA(aA, _ks + 1);                          \
            STEP(aB);                                                       \
        }                                                                   \
    }                                                                       \
} while (0)

    // Q0: compute from Bq0; fill Bq1 (q1 regs in flight), issue q2
    WRITE_FILL(1);
    ISSUE_FILL(12);
    QUARTER(0, 0);
    __syncthreads();   // Bq1 ready; Bq0 free

    // Q1: compute from Bq1; fill Bq0 with q2, issue q3
    WRITE_FILL(0);
    ISSUE_FILL(18);
    QUARTER(1, 6);
    __syncthreads();   // Bq0 ready; Bq1 free

    // Q2: compute from Bq0; fill Bq1 with q3 (k-steps 18-24 incl. bag chunk)
    WRITE_FILL(1);
    QUARTER(0, 12);
    __syncthreads();   // Bq1 ready

    // Q3: compute from Bq1 (6 emb steps + bag step at local chunk 6)
    QUARTER(1, 18);
    {
        short8 ab = *(const short8*)&bagb[w][lr][lg << 3];
        LDSB(1, 6);
        acc[0] = __builtin_amdgcn_mfma_f32_16x16x32_bf16(ab, bqr[0], acc[0], 0, 0, 0);
        acc[1] = __builtin_amdgcn_mfma_f32_16x16x32_bf16(ab, bqr[1], acc[1], 0, 0, 0);
        acc[2] = __builtin_amdgcn_mfma_f32_16x16x32_bf16(ab, bqr[2], acc[2], 0, 0, 0);
        acc[3] = __builtin_amdgcn_mfma_f32_16x16x32_bf16(ab, bqr[3], acc[3], 0, 0, 0);
    }

    // ================== epilogue: bias + relu + dot(W2) + tanh ===================
    float b1v[4], w2v[4];
#pragma unroll
    for (int ct = 0; ct < 4; ++ct) {
        int c = ct * 16 + lr;
        b1v[ct] = b1[c];
        w2v[ct] = W2[c];
    }
    const float b2v = b2[0];
#pragma unroll
    for (int r = 0; r < 4; ++r) {
        float p = 0.f;
#pragma unroll
        for (int ct = 0; ct < 4; ++ct) {
            float h = acc[ct][r] + b1v[ct];
            p += fmaxf(h, 0.f) * w2v[ct];
        }
        p += __shfl_xor(p, 1);
        p += __shfl_xor(p, 2);
        p += __shfl_xor(p, 4);
        p += __shfl_xor(p, 8);
        if (lr == 0)
            out[row0 + w * 16 + (lg << 2) + r] = tanhf(p + b2v);
    }
#undef ISSUE_FILL
#undef WRITE_FILL
#undef LOADA
#undef LDSB
#undef STEP
#undef QUARTER
}

extern "C" void kernel_launch(void* const* d_in, const int* in_sizes, int n_in,
                              void* d_out, int out_size, void* d_ws, size_t ws_size,
                              hipStream_t stream) {
    const float* emb   = (const float*)d_in[0];
    const int*   ids   = (const int*)d_in[1];
    const float* mask  = (const float*)d_in[2];
    const float* table = (const float*)d_in[3];
    const float* W1    = (const float*)d_in[4];
    const float* b1    = (const float*)d_in[5];
    const float* W2    = (const float*)d_in[6];
    const float* b2    = (const float*)d_in[7];
    float* out  = (float*)d_out;
    ushort* W1T = (ushort*)d_ws;   // 51200 bf16 = 100 KB

    prep_W1T<<<50, 256, 0, stream>>>(table, W1, W1T);
    const int nblocks = out_size / BM;   // 1024
    scorer_mfma<<<nblocks, 512, 0, stream>>>(emb, ids, mask, W1T, b1, W2, b2, out);
}